// Round 1
// baseline (959.876 us; speedup 1.0000x reference)
//
#include <hip/hip_runtime.h>
#include <hip/hip_bf16.h>

typedef __bf16 bf16x8 __attribute__((ext_vector_type(8)));
typedef float  f32x4  __attribute__((ext_vector_type(4)));

#define BM 64
#define LDS_STRIDE 520   // bf16 elems per row: 512 + 8 pad (keeps 16B align, breaks bank stride)

// ---------------- weight prepack ----------------
// Packs fp32 K x N row-major weights into bf16 MFMA B-fragment order:
// unit u = ((ntile*Kc + kc)*64 + lane), 8 bf16 per unit:
//   elem j: W[kc*32 + (lane>>4)*8 + j][ntile*16 + (lane&15)]
struct PrepParams {
    const float* src[9];
    int K[9];
    int N[9];
    int unitEnd[9];   // cumulative unit counts
};

__global__ void prep_weights(PrepParams p, unsigned short* __restrict__ dst) {
    int u = blockIdx.x * 256 + threadIdx.x;
    if (u >= p.unitEnd[8]) return;
    int w = 0;
    while (u >= p.unitEnd[w]) ++w;
    int base = (w == 0) ? 0 : p.unitEnd[w - 1];
    int lu = u - base;
    int K = p.K[w], N = p.N[w];
    int Kc = K >> 5;
    int perTile = Kc * 64;
    int ntile = lu / perTile;
    int rem = lu - ntile * perTile;
    int kc = rem >> 6;
    int lane = rem & 63;
    int k0 = kc * 32 + ((lane >> 4) << 3);
    int n = ntile * 16 + (lane & 15);
    const float* src = p.src[w];
    unsigned short* d = dst + (size_t)u * 8;
#pragma unroll
    for (int j = 0; j < 8; ++j) {
        float f = src[(size_t)(k0 + j) * N + n];
        __bf16 h = (__bf16)f;
        d[j] = __builtin_bit_cast(unsigned short, h);
    }
}

// ---------------- fused MLP ----------------
struct MlpParams {
    const float* X[3];
    const unsigned short* Wp[3];  // packed bf16 weights, per-type base (L1)
    const float* B1[3];
    const float* B2[3];
    const float* B3[3];
    int dIn[3];
    int Nt[3];
    int rowOff[3];
    int blkStart[3];
};

// One layer: A (BM x K bf16) from LDS, B from packed global weights, sigmoid epilogue.
// NT = n-tiles per wave (4 -> 64 cols/wave over 512; 2 -> 32 cols/wave over 256).
template <int NT, bool TO_LDS>
__device__ __forceinline__ void layer(
    const unsigned short* __restrict__ srcBuf,  // LDS
    unsigned short* __restrict__ dstBuf,        // LDS (TO_LDS)
    const unsigned short* __restrict__ W,       // packed global
    const float* __restrict__ bias,
    int K, int wave, int lane,
    float* __restrict__ gOut, int row0, int Nt) // global (!TO_LDS)
{
    const int Kc = K >> 5;
    const int quad = lane >> 4;
    const int lm = lane & 15;
    const int c0 = wave * NT * 16;

    f32x4 acc[4][NT];
#pragma unroll
    for (int i = 0; i < 4; ++i)
#pragma unroll
        for (int j = 0; j < NT; ++j)
            acc[i][j] = (f32x4){0.f, 0.f, 0.f, 0.f};

    for (int kc = 0; kc < Kc; ++kc) {
        bf16x8 a[4];
#pragma unroll
        for (int i = 0; i < 4; ++i) {
            const unsigned short* ap =
                srcBuf + (i * 16 + lm) * LDS_STRIDE + kc * 32 + quad * 8;
            a[i] = *(const bf16x8*)ap;
        }
#pragma unroll
        for (int j = 0; j < NT; ++j) {
            int ntg = wave * NT + j;
            const unsigned short* bp =
                W + ((size_t)(ntg * Kc + kc) * 64 + lane) * 8;
            bf16x8 bf = *(const bf16x8*)bp;
#pragma unroll
            for (int i = 0; i < 4; ++i)
                acc[i][j] = __builtin_amdgcn_mfma_f32_16x16x32_bf16(
                    a[i], bf, acc[i][j], 0, 0, 0);
        }
    }

#pragma unroll
    for (int j = 0; j < NT; ++j) {
        int col = c0 + j * 16 + lm;
        float bv = bias[col];
#pragma unroll
        for (int i = 0; i < 4; ++i) {
#pragma unroll
            for (int r = 0; r < 4; ++r) {
                int row = i * 16 + quad * 4 + r;
                float z = acc[i][j][r] + bv;
                float s = 1.0f / (1.0f + __expf(-z));
                if constexpr (TO_LDS) {
                    dstBuf[row * LDS_STRIDE + col] =
                        __builtin_bit_cast(unsigned short, (__bf16)s);
                } else {
                    if (row0 + row < Nt)
                        gOut[(size_t)row * 256 + col] = s;
                }
            }
        }
    }
}

__global__ void __launch_bounds__(512, 2)
mlp_fused(MlpParams p, float* __restrict__ out) {
    extern __shared__ unsigned short smem[];
    unsigned short* bufA = smem;                      // X then H2
    unsigned short* bufB = smem + BM * LDS_STRIDE;    // H1

    int b = blockIdx.x;
    int t = (b >= p.blkStart[1]) + (b >= p.blkStart[2]);
    int blk = b - p.blkStart[t];
    int dIn = p.dIn[t];
    int Nt = p.Nt[t];
    int row0 = blk * BM;
    const float* X = p.X[t];
    const unsigned short* W1 = p.Wp[t];
    const unsigned short* W2 = W1 + dIn * 512;
    const unsigned short* W3 = W2 + 512 * 512;

    int tid = threadIdx.x;
    int wave = tid >> 6;
    int lane = tid & 63;

    // ---- stage X (fp32 global -> bf16 LDS), zero-pad OOB rows ----
    int d4 = dIn >> 2;               // float4 per row (16/32/64)
    int s4 = 31 - __clz(d4);
    int nf4 = BM * d4;
    for (int i = tid; i < nf4; i += 512) {
        int r = i >> s4;
        int c4 = i & (d4 - 1);
        int grow = row0 + r;
        float4 v = make_float4(0.f, 0.f, 0.f, 0.f);
        if (grow < Nt) v = ((const float4*)X)[(size_t)grow * d4 + c4];
        ushort4 u;
        u.x = __builtin_bit_cast(unsigned short, (__bf16)v.x);
        u.y = __builtin_bit_cast(unsigned short, (__bf16)v.y);
        u.z = __builtin_bit_cast(unsigned short, (__bf16)v.z);
        u.w = __builtin_bit_cast(unsigned short, (__bf16)v.w);
        *(ushort4*)(bufA + r * LDS_STRIDE + c4 * 4) = u;
    }
    __syncthreads();

    // L1: X(bufA) @ W1 -> H1(bufB)    [BM x 512]
    layer<4, true>(bufA, bufB, W1, p.B1[t], dIn, wave, lane, nullptr, 0, 0);
    __syncthreads();
    // L2: H1(bufB) @ W2 -> H2(bufA)   [BM x 512]
    layer<4, true>(bufB, bufA, W2, p.B2[t], 512, wave, lane, nullptr, 0, 0);
    __syncthreads();
    // L3: H2(bufA) @ W3 -> out        [BM x 256]
    float* gOut = out + (size_t)(p.rowOff[t] + row0) * 256;
    layer<2, false>(bufA, nullptr, W3, p.B3[t], 512, wave, lane, gOut, row0, Nt);
}

// ---------------- launch ----------------
extern "C" void kernel_launch(void* const* d_in, const int* in_sizes, int n_in,
                              void* d_out, int out_size, void* d_ws, size_t ws_size,
                              hipStream_t stream) {
    const int IN0[3] = {64, 128, 256};
    const int CNT[3] = {100000, 80000, 60000};

    // ---- prepack weights into ws (bf16, fragment-ordered) ----
    PrepParams pp;
    int ue = 0;
    for (int t = 0; t < 3; ++t) {
        int Ks[3] = {IN0[t], 512, 512};
        int Ns[3] = {512, 512, 256};
        for (int l = 0; l < 3; ++l) {
            int w = t * 3 + l;
            pp.src[w] = (const float*)d_in[4 + t * 6 + l * 2];
            pp.K[w] = Ks[l];
            pp.N[w] = Ns[l];
            ue += (Ks[l] * Ns[l]) >> 3;
            pp.unitEnd[w] = ue;
        }
    }
    int prepBlocks = (ue + 255) / 256;   // ue = 176128 -> 688
    prep_weights<<<dim3(prepBlocks), dim3(256), 0, stream>>>(
        pp, (unsigned short*)d_ws);

    // ---- fused MLP ----
    MlpParams mp;
    int woff = 0, roff = 0, boff = 0;
    for (int t = 0; t < 3; ++t) {
        mp.X[t] = (const float*)d_in[t];
        mp.Wp[t] = (const unsigned short*)d_ws + woff;
        mp.B1[t] = (const float*)d_in[4 + t * 6 + 1];
        mp.B2[t] = (const float*)d_in[4 + t * 6 + 3];
        mp.B3[t] = (const float*)d_in[4 + t * 6 + 5];
        mp.dIn[t] = IN0[t];
        mp.Nt[t] = CNT[t];
        mp.rowOff[t] = roff;
        mp.blkStart[t] = boff;
        woff += IN0[t] * 512 + 512 * 512 + 512 * 256;
        roff += CNT[t];
        boff += (CNT[t] + BM - 1) / BM;
    }
    size_t lds = (size_t)2 * BM * LDS_STRIDE * sizeof(unsigned short); // 133,120 B
    mlp_fused<<<dim3(boff), dim3(512), lds, stream>>>(mp, (float*)d_out);
}

// Round 2
// 734.190 us; speedup vs baseline: 1.3074x; 1.3074x over previous
//
#include <hip/hip_runtime.h>
#include <hip/hip_bf16.h>

typedef __bf16 bf16x8 __attribute__((ext_vector_type(8)));
typedef float  f32x4  __attribute__((ext_vector_type(4)));

#define BM 64
#define LDS_STRIDE 520   // bf16 elems per row: 512 + 8 pad (16B-aligned rows)

// ---------------- weight prepack (coalesced, LDS-transpose) ----------------
// Output unit u = unitBase[w] + ((ntile*Kc + kc)*64 + lane), 8 bf16 per unit:
//   elem j: W[kc*32 + (lane>>4)*8 + j][ntile*16 + (lane&15)]
// One block per (w, kc, ngroup-of-128-cols): load 32x128 fp32 tile coalesced,
// emit 512 units as contiguous 16B stores.
struct Prep2Params {
    const float* src[9];
    int Kc[9];       // K/32
    int ngCnt[9];    // N/128
    int N[9];
    int blkEnd[9];   // cumulative block counts
    int unitBase[9]; // unit offset of matrix w in dst
};

__global__ void __launch_bounds__(256)
prep_weights2(Prep2Params p, unsigned short* __restrict__ dst) {
    __shared__ float tile[32][128];
    int b = blockIdx.x;
    int w = 0;
    while (b >= p.blkEnd[w]) ++w;
    int local = b - ((w == 0) ? 0 : p.blkEnd[w - 1]);
    int ngc = p.ngCnt[w];
    int kc = local / ngc;
    int ng = local - kc * ngc;
    const float* src = p.src[w];
    int N = p.N[w];
    int Kc = p.Kc[w];
    int t = threadIdx.x;

    int row0 = kc * 32, col0 = ng * 128;
#pragma unroll
    for (int i = 0; i < 4; ++i) {
        int e4 = t + i * 256;            // float4 index in 32x128 tile (1024 total)
        int r = e4 >> 5;                 // 32 float4 per row
        int c4 = e4 & 31;
        float4 v = *(const float4*)&src[(size_t)(row0 + r) * N + col0 + c4 * 4];
        *(float4*)&tile[r][c4 * 4] = v;
    }
    __syncthreads();

#pragma unroll
    for (int rep = 0; rep < 2; ++rep) {
        int ul = t + rep * 256;          // 512 units per block
        int ntl = ul >> 6;               // 0..7 local ntile
        int lane = ul & 63;
        int gUnit = p.unitBase[w] + ((ng * 8 + ntl) * Kc + kc) * 64 + lane;
        int lr = (lane >> 4) * 8;
        int lc = ntl * 16 + (lane & 15);
        alignas(16) unsigned short u8[8];
#pragma unroll
        for (int j = 0; j < 8; ++j)
            u8[j] = __builtin_bit_cast(unsigned short, (__bf16)tile[lr + j][lc]);
        *(uint4*)(dst + (size_t)gUnit * 8) = *(const uint4*)u8;
    }
}

// ---------------- fused MLP ----------------
struct MlpParams {
    const float* X[3];
    const unsigned short* Wp[3];  // packed bf16 weights, per-type base (L1)
    const float* B1[3];
    const float* B2[3];
    const float* B3[3];
    int dIn[3];
    int Nt[3];
    int rowOff[3];
    int blkStart[3];
};

// One layer, IN-PLACE on a single LDS buffer: compute full acc from srcBuf,
// barrier, then overwrite. NT = n-tiles per wave (4 -> 64 cols over 512;
// 2 -> 32 cols over 256).
template <int NT, bool TO_LDS>
__device__ __forceinline__ void layer(
    unsigned short* __restrict__ buf,           // LDS (src, and dst if TO_LDS)
    const unsigned short* __restrict__ W,       // packed global
    const float* __restrict__ bias,
    int K, int wave, int lane,
    float* __restrict__ gOut, int row0, int Nt) // global (!TO_LDS)
{
    const int Kc = K >> 5;
    const int quad = lane >> 4;
    const int lm = lane & 15;
    const int c0 = wave * NT * 16;

    f32x4 acc[4][NT];
#pragma unroll
    for (int i = 0; i < 4; ++i)
#pragma unroll
        for (int j = 0; j < NT; ++j)
            acc[i][j] = (f32x4){0.f, 0.f, 0.f, 0.f};

    for (int kc = 0; kc < Kc; ++kc) {
        bf16x8 a[4];
#pragma unroll
        for (int i = 0; i < 4; ++i) {
            const unsigned short* ap =
                buf + (i * 16 + lm) * LDS_STRIDE + kc * 32 + quad * 8;
            a[i] = *(const bf16x8*)ap;
        }
#pragma unroll
        for (int j = 0; j < NT; ++j) {
            int ntg = wave * NT + j;
            const unsigned short* bp =
                W + ((size_t)(ntg * Kc + kc) * 64 + lane) * 8;
            bf16x8 bf = *(const bf16x8*)bp;
#pragma unroll
            for (int i = 0; i < 4; ++i)
                acc[i][j] = __builtin_amdgcn_mfma_f32_16x16x32_bf16(
                    a[i], bf, acc[i][j], 0, 0, 0);
        }
    }

    if constexpr (TO_LDS)
        __syncthreads();   // all reads of buf complete before in-place write

#pragma unroll
    for (int j = 0; j < NT; ++j) {
        int col = c0 + j * 16 + lm;
        float bv = bias[col];
#pragma unroll
        for (int i = 0; i < 4; ++i) {
#pragma unroll
            for (int r = 0; r < 4; ++r) {
                int row = i * 16 + quad * 4 + r;
                float z = acc[i][j][r] + bv;
                float s = 1.0f / (1.0f + __expf(-z));
                if constexpr (TO_LDS) {
                    buf[row * LDS_STRIDE + col] =
                        __builtin_bit_cast(unsigned short, (__bf16)s);
                } else {
                    if (row0 + row < Nt)
                        gOut[(size_t)row * 256 + col] = s;
                }
            }
        }
    }
}

__global__ void __launch_bounds__(512, 4)   // 4 waves/EU -> 2 blocks/CU
mlp_fused(MlpParams p, float* __restrict__ out) {
    extern __shared__ unsigned short smem[];
    unsigned short* buf = smem;   // single 64 x 520 bf16 buffer (66.5 KB)

    int b = blockIdx.x;
    int t = (b >= p.blkStart[1]) + (b >= p.blkStart[2]);
    int blk = b - p.blkStart[t];
    int dIn = p.dIn[t];
    int Nt = p.Nt[t];
    int row0 = blk * BM;
    const float* X = p.X[t];
    const unsigned short* W1 = p.Wp[t];
    const unsigned short* W2 = W1 + dIn * 512;
    const unsigned short* W3 = W2 + 512 * 512;

    int tid = threadIdx.x;
    int wave = tid >> 6;
    int lane = tid & 63;

    // ---- stage X (fp32 global -> bf16 LDS), zero-pad OOB rows ----
    int d4 = dIn >> 2;               // float4 per row (16/32/64)
    int s4 = 31 - __clz(d4);
    int nf4 = BM * d4;
    for (int i = tid; i < nf4; i += 512) {
        int r = i >> s4;
        int c4 = i & (d4 - 1);
        int grow = row0 + r;
        float4 v = make_float4(0.f, 0.f, 0.f, 0.f);
        if (grow < Nt) v = ((const float4*)X)[(size_t)grow * d4 + c4];
        ushort4 u;
        u.x = __builtin_bit_cast(unsigned short, (__bf16)v.x);
        u.y = __builtin_bit_cast(unsigned short, (__bf16)v.y);
        u.z = __builtin_bit_cast(unsigned short, (__bf16)v.z);
        u.w = __builtin_bit_cast(unsigned short, (__bf16)v.w);
        *(ushort4*)(buf + r * LDS_STRIDE + c4 * 4) = u;
    }
    __syncthreads();

    // L1: X -> H1 (in place)   [BM x 512]
    layer<4, true>(buf, W1, p.B1[t], dIn, wave, lane, nullptr, 0, 0);
    __syncthreads();
    // L2: H1 -> H2 (in place)  [BM x 512]
    layer<4, true>(buf, W2, p.B2[t], 512, wave, lane, nullptr, 0, 0);
    __syncthreads();
    // L3: H2 -> out            [BM x 256]
    float* gOut = out + (size_t)(p.rowOff[t] + row0) * 256;
    layer<2, false>(buf, W3, p.B3[t], 512, wave, lane, gOut, row0, Nt);
}

// ---------------- launch ----------------
extern "C" void kernel_launch(void* const* d_in, const int* in_sizes, int n_in,
                              void* d_out, int out_size, void* d_ws, size_t ws_size,
                              hipStream_t stream) {
    const int IN0[3] = {64, 128, 256};
    const int CNT[3] = {100000, 80000, 60000};

    // ---- prepack weights into ws (bf16, fragment-ordered) ----
    Prep2Params pp;
    int blocks = 0, ubase = 0;
    for (int t = 0; t < 3; ++t) {
        int Ks[3] = {IN0[t], 512, 512};
        int Ns[3] = {512, 512, 256};
        for (int l = 0; l < 3; ++l) {
            int w = t * 3 + l;
            pp.src[w] = (const float*)d_in[4 + t * 6 + l * 2];
            pp.Kc[w] = Ks[l] >> 5;
            pp.ngCnt[w] = Ns[l] >> 7;
            pp.N[w] = Ns[l];
            pp.unitBase[w] = ubase;
            blocks += pp.Kc[w] * pp.ngCnt[w];
            pp.blkEnd[w] = blocks;
            ubase += (Ks[l] * Ns[l]) >> 3;
        }
    }
    prep_weights2<<<dim3(blocks), dim3(256), 0, stream>>>(
        pp, (unsigned short*)d_ws);

    // ---- fused MLP ----
    MlpParams mp;
    int woff = 0, roff = 0, boff = 0;
    for (int t = 0; t < 3; ++t) {
        mp.X[t] = (const float*)d_in[t];
        mp.Wp[t] = (const unsigned short*)d_ws + woff;
        mp.B1[t] = (const float*)d_in[4 + t * 6 + 1];
        mp.B2[t] = (const float*)d_in[4 + t * 6 + 3];
        mp.B3[t] = (const float*)d_in[4 + t * 6 + 5];
        mp.dIn[t] = IN0[t];
        mp.Nt[t] = CNT[t];
        mp.rowOff[t] = roff;
        mp.blkStart[t] = boff;
        woff += IN0[t] * 512 + 512 * 512 + 512 * 256;
        roff += CNT[t];
        boff += (CNT[t] + BM - 1) / BM;
    }
    size_t lds = (size_t)BM * LDS_STRIDE * sizeof(unsigned short); // 66,560 B
    mlp_fused<<<dim3(boff), dim3(512), lds, stream>>>(mp, (float*)d_out);
}

// Round 3
// 650.532 us; speedup vs baseline: 1.4755x; 1.1286x over previous
//
#include <hip/hip_runtime.h>
#include <hip/hip_bf16.h>

typedef __bf16 bf16x8 __attribute__((ext_vector_type(8)));
typedef __bf16 bf16x4 __attribute__((ext_vector_type(4)));
typedef float  f32x16 __attribute__((ext_vector_type(16)));

#define BM 64            // batch rows per block (2 N-tiles of 32)
#define S  520           // bf16 elems per LDS activation row (512 + 8)
#define SF 260           // f32 elems per LDS row for out staging (same 1040 B)

// ---------------- weight prepack ----------------
// Transposed formulation: A-operand = W^T for v_mfma_f32_32x32x16_bf16.
// A[m][k]: m = lane&31 (out-feature), k = (lane>>5)*8 + j.
// Packed unit u = unitBase[w] + ((mt*Kc + kc)*64 + lane), Kc = K/16; 8 bf16:
//   elem j = W[kc*16 + (lane>>5)*8 + j][mt*32 + (lane&31)]
struct PrepParams {
    const float* src[9];
    int Kt[9];       // K/32
    int Mg[9];       // N/128 (col groups)
    int N[9];
    int blkEnd[9];
    int unitBase[9];
};

__global__ void __launch_bounds__(256)
prep_weights(PrepParams p, uint4* __restrict__ dst) {
    __shared__ float tile[32][128];
    int b = blockIdx.x;
    int w = 0;
    while (b >= p.blkEnd[w]) ++w;
    int local = b - ((w == 0) ? 0 : p.blkEnd[w - 1]);
    int mgc = p.Mg[w];
    int kt = local / mgc;
    int mg = local - kt * mgc;
    const float* src = p.src[w];
    int N = p.N[w];
    int Kc = p.Kt[w] * 2;
    int t = threadIdx.x;

    int row0 = kt * 32, col0 = mg * 128;
#pragma unroll
    for (int i = 0; i < 4; ++i) {
        int e4 = t + i * 256;            // 1024 float4 in 32x128 tile
        int r = e4 >> 5;
        int c4 = e4 & 31;
        float4 v = *(const float4*)&src[(size_t)(row0 + r) * N + col0 + c4 * 4];
        *(float4*)&tile[r][c4 * 4] = v;
    }
    __syncthreads();

#pragma unroll
    for (int rep = 0; rep < 2; ++rep) {
        int ul = t + rep * 256;          // 512 units per block
        int lane = ul & 63;
        int kcl = (ul >> 6) & 1;
        int mtl = ul >> 7;               // 0..3
        int gUnit = p.unitBase[w] +
                    ((mg * 4 + mtl) * Kc + (kt * 2 + kcl)) * 64 + lane;
        int lr = kcl * 16 + ((lane >> 5) << 3);
        int lc = mtl * 32 + (lane & 31);
        alignas(16) unsigned short u8[8];
#pragma unroll
        for (int j = 0; j < 8; ++j)
            u8[j] = __builtin_bit_cast(unsigned short, (__bf16)tile[lr + j][lc]);
        dst[gUnit] = *(const uint4*)u8;
    }
}

// ---------------- fused MLP ----------------
struct MlpParams {
    const float* X[3];
    const unsigned short* Wp[3];
    const float* B1[3];
    const float* B2[3];
    const float* B3[3];
    int dIn[3];
    int Nt[3];
    int rowOff[3];
    int blkStart[3];
};

__device__ __forceinline__ float sigmoidf(float z) {
    return __builtin_amdgcn_rcpf(
        1.0f + __builtin_amdgcn_exp2f(-1.442695040888963f * z));
}

// Transposed layer: D[feature][batch] = W^T (A, from packed global) x
// H (B, from LDS rows [batch][feature]). Wave owns MT feature-tiles (32 each)
// x 2 batch-tiles (rows 0-31, 32-63). C/D: batchcol = lane&31,
// featrow = (reg&3) + 8*(reg>>2) + 4*(lane>>5)  -> 4 consecutive features
// per reg-quad => packed b64 LDS writes / float4 out writes.
template <int MT, bool TO_LDS>
__device__ __forceinline__ void layer(
    unsigned short* __restrict__ buf,
    const unsigned short* __restrict__ W,
    const float* __restrict__ bias,
    int K, int wave, int lane)
{
    const int Kc = K >> 4;
    const int half = lane >> 5;
    const int lr = lane & 31;

    f32x16 acc[2][MT];
#pragma unroll
    for (int n = 0; n < 2; ++n)
#pragma unroll
        for (int m = 0; m < MT; ++m)
#pragma unroll
            for (int e = 0; e < 16; ++e)
                acc[n][m][e] = 0.0f;

    const unsigned short* bp0 = buf + lr * S + half * 8;       // batch rows 0..31
    const unsigned short* bp1 = bp0 + 32 * S;                  // batch rows 32..63
    const unsigned short* ap = W + (size_t)wave * MT * Kc * 512 + lane * 8;

    for (int kc = 0; kc < Kc; ++kc) {
        bf16x8 b0 = *(const bf16x8*)(bp0 + kc * 16);
        bf16x8 b1 = *(const bf16x8*)(bp1 + kc * 16);
#pragma unroll
        for (int m = 0; m < MT; ++m) {
            bf16x8 a = *(const bf16x8*)(ap + ((size_t)m * Kc + kc) * 512);
            acc[0][m] = __builtin_amdgcn_mfma_f32_32x32x16_bf16(
                a, b0, acc[0][m], 0, 0, 0);
            acc[1][m] = __builtin_amdgcn_mfma_f32_32x32x16_bf16(
                a, b1, acc[1][m], 0, 0, 0);
        }
    }

    __syncthreads();   // all waves' B-reads done before in-place overwrite

#pragma unroll
    for (int m = 0; m < MT; ++m) {
        int mt = wave * MT + m;
#pragma unroll
        for (int g = 0; g < 4; ++g) {
            int f0 = mt * 32 + g * 8 + half * 4;   // 4 consecutive features
            float4 bv = *(const float4*)(bias + f0);
#pragma unroll
            for (int n = 0; n < 2; ++n) {
                int r = n * 32 + lr;
                float s0 = sigmoidf(acc[n][m][g * 4 + 0] + bv.x);
                float s1 = sigmoidf(acc[n][m][g * 4 + 1] + bv.y);
                float s2 = sigmoidf(acc[n][m][g * 4 + 2] + bv.z);
                float s3 = sigmoidf(acc[n][m][g * 4 + 3] + bv.w);
                if constexpr (TO_LDS) {
                    bf16x4 h = {(__bf16)s0, (__bf16)s1, (__bf16)s2, (__bf16)s3};
                    *(bf16x4*)(buf + r * S + f0) = h;      // packed b64
                } else {
                    float* fb = (float*)buf;
                    *(float4*)(fb + r * SF + f0) =
                        make_float4(s0, s1, s2, s3);        // b128
                }
            }
        }
    }
}

__global__ void __launch_bounds__(512, 4)   // 2 blocks/CU (LDS 66.5 KB) -> 16 waves/CU
mlp_fused(MlpParams p, float* __restrict__ out) {
    extern __shared__ unsigned short buf[];

    int b = blockIdx.x;
    int t = (b >= p.blkStart[1]) + (b >= p.blkStart[2]);
    int blk = b - p.blkStart[t];
    int dIn = p.dIn[t];
    int Nt = p.Nt[t];
    int row0 = blk * BM;
    const float* X = p.X[t];
    const unsigned short* W1 = p.Wp[t];
    const unsigned short* W2 = W1 + dIn * 512;
    const unsigned short* W3 = W2 + 512 * 512;

    int tid = threadIdx.x;
    int wave = tid >> 6;
    int lane = tid & 63;

    // ---- stage X (fp32 global -> bf16 LDS rows [batch][feat]) ----
    int d4 = dIn >> 2;               // float4 per row (16/32/64)
    int s4 = 31 - __clz(d4);
    int nf4 = BM * d4;
    for (int i = tid; i < nf4; i += 512) {
        int r = i >> s4;
        int c4 = i & (d4 - 1);
        int grow = row0 + r;
        float4 v = make_float4(0.f, 0.f, 0.f, 0.f);
        if (grow < Nt) v = ((const float4*)X)[(size_t)grow * d4 + c4];
        ushort4 u;
        u.x = __builtin_bit_cast(unsigned short, (__bf16)v.x);
        u.y = __builtin_bit_cast(unsigned short, (__bf16)v.y);
        u.z = __builtin_bit_cast(unsigned short, (__bf16)v.z);
        u.w = __builtin_bit_cast(unsigned short, (__bf16)v.w);
        *(ushort4*)(buf + r * S + c4 * 4) = u;
    }
    __syncthreads();

    // L1: X -> H1 in place    (512 feats, 2 mtiles/wave)
    layer<2, true>(buf, W1, p.B1[t], dIn, wave, lane);
    __syncthreads();
    // L2: H1 -> H2 in place   (512 feats)
    layer<2, true>(buf, W2, p.B2[t], 512, wave, lane);
    __syncthreads();
    // L3: H2 -> f32 staging   (256 feats, 1 mtile/wave)
    layer<1, false>(buf, W3, p.B3[t], 512, wave, lane);
    __syncthreads();

    // ---- coalesced output store: 64 rows x 256 f32, full 1KB rows ----
    const float* fb = (const float*)buf;
    float* gOut = out + (size_t)(p.rowOff[t] + row0) * 256;
    for (int i = tid; i < BM * 64; i += 512) {   // 4096 float4
        int r = i >> 6;
        int c4 = i & 63;
        if (row0 + r < Nt)
            *(float4*)(gOut + r * 256 + c4 * 4) =
                *(const float4*)(fb + r * SF + c4 * 4);
    }
}

// ---------------- launch ----------------
extern "C" void kernel_launch(void* const* d_in, const int* in_sizes, int n_in,
                              void* d_out, int out_size, void* d_ws, size_t ws_size,
                              hipStream_t stream) {
    const int IN0[3] = {64, 128, 256};
    const int CNT[3] = {100000, 80000, 60000};

    // ---- prepack weights into ws (bf16, A-fragment-ordered for 32x32x16) ----
    PrepParams pp;
    int blocks = 0, ubase = 0;
    for (int t = 0; t < 3; ++t) {
        int Ks[3] = {IN0[t], 512, 512};
        int Ns[3] = {512, 512, 256};
        for (int l = 0; l < 3; ++l) {
            int w = t * 3 + l;
            pp.src[w] = (const float*)d_in[4 + t * 6 + l * 2];
            pp.Kt[w] = Ks[l] >> 5;
            pp.Mg[w] = Ns[l] >> 7;
            pp.N[w] = Ns[l];
            pp.unitBase[w] = ubase;
            blocks += pp.Kt[w] * pp.Mg[w];
            pp.blkEnd[w] = blocks;
            ubase += (Ks[l] * Ns[l]) >> 3;
        }
    }
    prep_weights<<<dim3(blocks), dim3(256), 0, stream>>>(pp, (uint4*)d_ws);

    // ---- fused MLP ----
    MlpParams mp;
    int woff = 0, roff = 0, boff = 0;
    for (int t = 0; t < 3; ++t) {
        mp.X[t] = (const float*)d_in[t];
        mp.Wp[t] = (const unsigned short*)d_ws + woff;
        mp.B1[t] = (const float*)d_in[4 + t * 6 + 1];
        mp.B2[t] = (const float*)d_in[4 + t * 6 + 3];
        mp.B3[t] = (const float*)d_in[4 + t * 6 + 5];
        mp.dIn[t] = IN0[t];
        mp.Nt[t] = CNT[t];
        mp.rowOff[t] = roff;
        mp.blkStart[t] = boff;
        woff += IN0[t] * 512 + 512 * 512 + 512 * 256;
        roff += CNT[t];
        boff += (CNT[t] + BM - 1) / BM;
    }
    size_t lds = (size_t)BM * S * sizeof(unsigned short);   // 66,560 B
    mlp_fused<<<dim3(boff), dim3(512), lds, stream>>>(mp, (float*)d_out);
}